// Round 1
// baseline (397.572 us; speedup 1.0000x reference)
//
#include <hip/hip_runtime.h>
#include <hip/hip_bf16.h>

// Sizes are fixed by the reference:
// B=2, LQ=LKV=1024, H=8, DQK=DV=64, DQ=DK=DVIN=DOUT=512, SPAN=128, STRIDE=1
#define LQ 1024
#define NH 8
#define DHEAD 64
#define DMODEL 512
#define SPAN 128
#define MROWS 2048   // B*LQ

// ---------------------------------------------------------------------------
// f32 tiled GEMM: C[M=2048, N=512] = A[2048, 512] @ W[512, 512]
// scatter=1: write C to (B, H, LQ, 64) layout (projection outputs)
// scatter=0: plain row-major (final output)
// ---------------------------------------------------------------------------
__global__ __launch_bounds__(256) void gemm512_f32(
    const float* __restrict__ A, const float* __restrict__ W,
    float* __restrict__ C, int scatter)
{
    __shared__ float As[64][17];   // [row][k] padded
    __shared__ float Bs[16][65];   // [k][col] padded

    const int tid = threadIdx.x;
    const int tx = tid & 15;        // 16 col groups
    const int ty = tid >> 4;        // 16 row groups
    const int m0 = blockIdx.y * 64;
    const int n0 = blockIdx.x * 64;

    float acc[4][4] = {};

    for (int k0 = 0; k0 < DMODEL; k0 += 16) {
        #pragma unroll
        for (int i = 0; i < 4; ++i) {
            int lin = tid + i * 256;
            int r = lin >> 4, c = lin & 15;
            As[r][c] = A[(size_t)(m0 + r) * DMODEL + k0 + c];
        }
        #pragma unroll
        for (int i = 0; i < 4; ++i) {
            int lin = tid + i * 256;
            int r = lin >> 6, c = lin & 63;
            Bs[r][c] = W[(size_t)(k0 + r) * DMODEL + n0 + c];
        }
        __syncthreads();
        #pragma unroll
        for (int kk = 0; kk < 16; ++kk) {
            float a[4], b[4];
            #pragma unroll
            for (int i = 0; i < 4; ++i) a[i] = As[ty * 4 + i][kk];
            #pragma unroll
            for (int j = 0; j < 4; ++j) b[j] = Bs[kk][tx * 4 + j];
            #pragma unroll
            for (int i = 0; i < 4; ++i)
                #pragma unroll
                for (int j = 0; j < 4; ++j)
                    acc[i][j] += a[i] * b[j];
        }
        __syncthreads();
    }

    #pragma unroll
    for (int i = 0; i < 4; ++i) {
        int m = m0 + ty * 4 + i;
        #pragma unroll
        for (int j = 0; j < 4; ++j) {
            int n = n0 + tx * 4 + j;
            if (scatter) {
                // m = b*1024 + jq ; n = h*64 + d  ->  ((b*8+h)*1024 + jq)*64 + d
                int b = m >> 10, jq = m & 1023;
                int h = n >> 6, d = n & 63;
                C[((((size_t)b * NH + h) * LQ) + jq) * DHEAD + d] = acc[i][j];
            } else {
                C[(size_t)m * DMODEL + n] = acc[i][j];
            }
        }
    }
}

// ---------------------------------------------------------------------------
// Sliding-window attention. One wave (64 lanes) per query; lane = d channel.
// Q,K,V layout: (B*H, LQ, 64). Output layout: (B, LQ, H, 64) so the final
// GEMM can treat it as row-major (2048, 512).
// ---------------------------------------------------------------------------
__global__ __launch_bounds__(256) void attn_win(
    const float* __restrict__ Q, const float* __restrict__ K,
    const float* __restrict__ V, float* __restrict__ O)
{
    __shared__ float sc[4][SPAN];

    const int w = threadIdx.x >> 6;
    const int lane = threadIdx.x & 63;
    const int bh = blockIdx.y;                 // 0..15
    const int j = blockIdx.x * 4 + w;          // query index 0..1023

    const float* qp = Q + ((size_t)bh * LQ + j) * DHEAD;
    const float* Kb = K + (size_t)bh * LQ * DHEAD;
    const float* Vb = V + (size_t)bh * LQ * DHEAD;

    const float qv = qp[lane];

    // scores
    for (int s = 0; s < SPAN; ++s) {
        int kv = j - (SPAN - 1) + s;
        float score = -1e30f;
        if (kv >= 0) {
            float p = qv * Kb[(size_t)kv * DHEAD + lane];
            #pragma unroll
            for (int off = 32; off; off >>= 1) p += __shfl_xor(p, off);
            score = p * 0.125f;   // 1/sqrt(64)
        }
        if (lane == 0) sc[w][s] = score;
    }
    __syncthreads();

    // softmax over 128 scores (2 per lane)
    float s0 = sc[w][lane];
    float s1 = sc[w][lane + 64];
    float m = fmaxf(s0, s1);
    #pragma unroll
    for (int off = 32; off; off >>= 1) m = fmaxf(m, __shfl_xor(m, off));
    float p0 = __expf(s0 - m);
    float p1 = __expf(s1 - m);
    float sum = p0 + p1;
    #pragma unroll
    for (int off = 32; off; off >>= 1) sum += __shfl_xor(sum, off);
    float inv = 1.0f / sum;
    sc[w][lane]      = p0 * inv;
    sc[w][lane + 64] = p1 * inv;
    __syncthreads();

    // weighted V accumulate
    float acc = 0.0f;
    int lo = j - (SPAN - 1); if (lo < 0) lo = 0;
    for (int kv = lo; kv <= j; ++kv) {
        float wgt = sc[w][kv - (j - (SPAN - 1))];
        acc += wgt * Vb[(size_t)kv * DHEAD + lane];
    }

    int b = bh >> 3, h = bh & 7;
    O[(((size_t)b * LQ + j) * NH + h) * DHEAD + lane] = acc;
}

// ---------------------------------------------------------------------------
extern "C" void kernel_launch(void* const* d_in, const int* in_sizes, int n_in,
                              void* d_out, int out_size, void* d_ws, size_t ws_size,
                              hipStream_t stream) {
    const float* q  = (const float*)d_in[0];
    const float* k  = (const float*)d_in[1];
    const float* v  = (const float*)d_in[2];
    const float* Wq = (const float*)d_in[3];
    const float* Wk = (const float*)d_in[4];
    const float* Wv = (const float*)d_in[5];
    const float* Wo = (const float*)d_in[6];

    float* ws = (float*)d_ws;
    const size_t TSZ = (size_t)MROWS * DMODEL;   // 1M floats per tensor
    float* Qp = ws;
    float* Kp = ws + TSZ;
    float* Vp = ws + 2 * TSZ;
    float* Ah = ws + 3 * TSZ;

    dim3 ggrid(DMODEL / 64, MROWS / 64);  // (8, 32)

    gemm512_f32<<<ggrid, 256, 0, stream>>>(q, Wq, Qp, 1);
    gemm512_f32<<<ggrid, 256, 0, stream>>>(k, Wk, Kp, 1);
    gemm512_f32<<<ggrid, 256, 0, stream>>>(v, Wv, Vp, 1);

    attn_win<<<dim3(LQ / 4, 16), 256, 0, stream>>>(Qp, Kp, Vp, Ah);

    gemm512_f32<<<ggrid, 256, 0, stream>>>(Ah, Wo, (float*)d_out, 0);
}

// Round 2
// 137.952 us; speedup vs baseline: 2.8820x; 2.8820x over previous
//
#include <hip/hip_runtime.h>
#include <hip/hip_bf16.h>

// B=2, LQ=LKV=1024, H=8, DQK=DV=64, DQ=DK=DVIN=DOUT=512, SPAN=128, STRIDE=1
#define LQ 1024
#define NH 8
#define DHEAD 64
#define DMODEL 512
#define SPAN 128
#define MROWS 2048   // B*LQ

typedef __attribute__((ext_vector_type(8))) short   bf16x8;
typedef __attribute__((ext_vector_type(4))) float   f32x4;
typedef __attribute__((ext_vector_type(8))) unsigned short us8;

static __device__ __forceinline__ unsigned short f2bf(float f) {
    union { __hip_bfloat16 h; unsigned short u; } cv;
    cv.h = __float2bfloat16(f);
    return cv.u;
}

static __device__ __forceinline__ void gload_lds16(const void* g, void* l) {
    __builtin_amdgcn_global_load_lds((const __attribute__((address_space(1))) void*)g,
                                     (__attribute__((address_space(3))) void*)l, 16, 0, 0);
}

// ---------------------------------------------------------------------------
// Prep 1: cast q,k,v (f32 [2048][512]) -> bf16
// ---------------------------------------------------------------------------
__global__ __launch_bounds__(256) void cast_bf16_3(
    const float* __restrict__ q, const float* __restrict__ k, const float* __restrict__ v,
    unsigned short* __restrict__ Aq, unsigned short* __restrict__ Ak, unsigned short* __restrict__ Av)
{
    const float* src = blockIdx.y == 0 ? q : (blockIdx.y == 1 ? k : v);
    unsigned short* dst = blockIdx.y == 0 ? Aq : (blockIdx.y == 1 ? Ak : Av);
    int i = (blockIdx.x * 256 + threadIdx.x) * 8;
    float4 f0 = *(const float4*)&src[i];
    float4 f1 = *(const float4*)&src[i + 4];
    us8 o;
    o[0] = f2bf(f0.x); o[1] = f2bf(f0.y); o[2] = f2bf(f0.z); o[3] = f2bf(f0.w);
    o[4] = f2bf(f1.x); o[5] = f2bf(f1.y); o[6] = f2bf(f1.z); o[7] = f2bf(f1.w);
    *(us8*)&dst[i] = o;
}

// ---------------------------------------------------------------------------
// Prep 2: transpose+cast weights: Wt[n][k] = bf16(W[k][n]), 512x512 each
// ---------------------------------------------------------------------------
__global__ __launch_bounds__(256) void transposeW(
    const float* __restrict__ W0, const float* __restrict__ W1,
    const float* __restrict__ W2, const float* __restrict__ W3,
    unsigned short* __restrict__ T0, unsigned short* __restrict__ T1,
    unsigned short* __restrict__ T2, unsigned short* __restrict__ T3)
{
    const float* W = blockIdx.z == 0 ? W0 : blockIdx.z == 1 ? W1 : blockIdx.z == 2 ? W2 : W3;
    unsigned short* T = blockIdx.z == 0 ? T0 : blockIdx.z == 1 ? T1 : blockIdx.z == 2 ? T2 : T3;
    __shared__ unsigned short sT[64][72];
    int c = threadIdx.x & 63;
    int r0 = (threadIdx.x >> 6) * 16;
    int n0 = blockIdx.x * 64, k0 = blockIdx.y * 64;
    #pragma unroll
    for (int i = 0; i < 16; ++i) {
        int r = r0 + i;
        sT[c][r] = f2bf(W[(size_t)(k0 + r) * DMODEL + n0 + c]);
    }
    __syncthreads();
    #pragma unroll
    for (int i = 0; i < 16; ++i) {
        int r = r0 + i;
        T[(size_t)(n0 + r) * DMODEL + k0 + c] = sT[r][c];
    }
}

// ---------------------------------------------------------------------------
// bf16 MFMA GEMM: C[M=2048][N=512] = A[M][K=512] @ W[K][N], A bf16 row-major,
// Bt = W^T bf16 [N][K] row-major. Tile 64x64, BK=64, 4 waves (2x2), dbuf LDS.
// MODE 0: C f32 row-major.  MODE 1: scatter f32 to (B,H,LQ,64).
// MODE 2: write C^T (swapped operands) f32 to (B,H,64,LQ)  [K-transposed]
// ---------------------------------------------------------------------------
template<int MODE>
__global__ __launch_bounds__(256) void gemm_bf16(
    const unsigned short* __restrict__ A, const unsigned short* __restrict__ Bt,
    float* __restrict__ C)
{
    __shared__ unsigned short As[2][4096];   // 64 rows x 64 k, swizzled, 8 KB each
    __shared__ unsigned short Bs[2][4096];

    const int tid = threadIdx.x;
    const int lane = tid & 63;
    const int w = tid >> 6;           // 4 waves
    const int wm = w >> 1, wn = w & 1;
    const int m0 = blockIdx.y * 64;
    const int n0 = blockIdx.x * 64;

    // storage rule: element (row,kg) at byte row*128 + (kg^(row&7))*16
    const int srow = lane >> 3;          // 0..7  (row within 8-row call group)
    const int sgrp = (lane & 7) ^ srow;  // pre-swizzled global k-group

    f32x4 acc[2][2];
    #pragma unroll
    for (int i = 0; i < 2; ++i)
        #pragma unroll
        for (int j = 0; j < 2; ++j)
            acc[i][j] = f32x4{0.f, 0.f, 0.f, 0.f};

    auto stage = [&](int buf, int kt) {
        const int k0 = kt * 64;
        #pragma unroll
        for (int cc = 0; cc < 2; ++cc) {
            int call = w * 2 + cc;           // 0..7, covers rows [call*8, call*8+8)
            int row = call * 8 + srow;
            const unsigned short* gA = A + (size_t)(m0 + row) * DMODEL + k0 + (sgrp << 3);
            gload_lds16(gA, &As[buf][call * 512]);
            const unsigned short* gB = Bt + (size_t)(n0 + row) * DMODEL + k0 + (sgrp << 3);
            gload_lds16(gB, &Bs[buf][call * 512]);
        }
    };

    const int frow = lane & 15;      // fragment row/col within 16
    const int fkg  = lane >> 4;      // k-group 0..3 within k-step

    auto ldfrag = [&](const unsigned short* base, int rb, int ks) -> bf16x8 {
        int row = rb * 16 + frow;
        int kg = ks * 4 + fkg;
        int off = row * 64 + ((kg ^ (row & 7)) << 3);   // ushort index
        return *(const bf16x8*)&base[off];
    };

    stage(0, 0);
    __syncthreads();

    for (int kt = 0; kt < 8; ++kt) {
        int buf = kt & 1;
        if (kt < 7) stage(buf ^ 1, kt + 1);
        #pragma unroll
        for (int ks = 0; ks < 2; ++ks) {
            bf16x8 a0, a1, b0, b1;
            if constexpr (MODE == 2) {
                a0 = ldfrag(Bs[buf], wn * 2 + 0, ks);
                a1 = ldfrag(Bs[buf], wn * 2 + 1, ks);
                b0 = ldfrag(As[buf], wm * 2 + 0, ks);
                b1 = ldfrag(As[buf], wm * 2 + 1, ks);
            } else {
                a0 = ldfrag(As[buf], wm * 2 + 0, ks);
                a1 = ldfrag(As[buf], wm * 2 + 1, ks);
                b0 = ldfrag(Bs[buf], wn * 2 + 0, ks);
                b1 = ldfrag(Bs[buf], wn * 2 + 1, ks);
            }
            acc[0][0] = __builtin_amdgcn_mfma_f32_16x16x32_bf16(a0, b0, acc[0][0], 0, 0, 0);
            acc[0][1] = __builtin_amdgcn_mfma_f32_16x16x32_bf16(a0, b1, acc[0][1], 0, 0, 0);
            acc[1][0] = __builtin_amdgcn_mfma_f32_16x16x32_bf16(a1, b0, acc[1][0], 0, 0, 0);
            acc[1][1] = __builtin_amdgcn_mfma_f32_16x16x32_bf16(a1, b1, acc[1][1], 0, 0, 0);
        }
        __syncthreads();
    }

    // C/D layout: col = lane&15, row = (lane>>4)*4 + r   [m89-verified]
    #pragma unroll
    for (int i = 0; i < 2; ++i) {
        #pragma unroll
        for (int j = 0; j < 2; ++j) {
            #pragma unroll
            for (int r = 0; r < 4; ++r) {
                if constexpr (MODE == 2) {
                    // acc rows = n-dim, cols = m-dim
                    int n = n0 + wn * 32 + i * 16 + (lane >> 4) * 4 + r;
                    int m = m0 + wm * 32 + j * 16 + (lane & 15);
                    int b = m >> 10, jq = m & 1023, h = n >> 6, d = n & 63;
                    C[(((size_t)(b * NH + h) * DHEAD) + d) * LQ + jq] = acc[i][j][r];
                } else {
                    int m = m0 + wm * 32 + i * 16 + (lane >> 4) * 4 + r;
                    int n = n0 + wn * 32 + j * 16 + (lane & 15);
                    if constexpr (MODE == 1) {
                        int b = m >> 10, jq = m & 1023, h = n >> 6, d = n & 63;
                        C[(((size_t)(b * NH + h) * LQ) + jq) * DHEAD + d] = acc[i][j][r];
                    } else {
                        C[(size_t)m * DMODEL + n] = acc[i][j][r];
                    }
                }
            }
        }
    }
}

// ---------------------------------------------------------------------------
// Sliding-window attention v2 (f32). One wave per query, 4 queries/block.
// Qp: (BH, LQ, 64)   Kt: (BH, 64, LQ)  [transposed]   Vp: (BH, LQ, 64)
// Output: bf16 (B, LQ, H*64) row-major for the final GEMM.
// QK phase: lane = kv-slot (2 slots per lane); PV phase: lane = d.
// ---------------------------------------------------------------------------
__global__ __launch_bounds__(256) void attn_win2(
    const float* __restrict__ Qp, const float* __restrict__ Kt,
    const float* __restrict__ Vp, unsigned short* __restrict__ O)
{
    __shared__ float sQ[4][64];
    __shared__ float sP[4][SPAN];

    const int w = threadIdx.x >> 6;
    const int lane = threadIdx.x & 63;
    const int bh = blockIdx.y;
    const int j = blockIdx.x * 4 + w;

    const float* KT = Kt + (size_t)bh * DHEAD * LQ;   // [d][kv]
    const float* V  = Vp + (size_t)bh * LQ * DHEAD;   // [kv][d]

    sQ[w][lane] = Qp[((size_t)bh * LQ + j) * DHEAD + lane];
    __syncthreads();

    // ---- scores: lane covers kv slots s=lane and s=lane+64 ----
    const int kv0 = j - (SPAN - 1) + lane;
    const int kv1 = kv0 + 64;
    const int c0 = kv0 < 0 ? 0 : kv0;
    const int c1 = kv1 < 0 ? 0 : kv1;
    float d0 = 0.f, d1 = 0.f;
    #pragma unroll
    for (int dd = 0; dd < DHEAD; ++dd) {
        float qd = sQ[w][dd];
        const float* Krow = KT + (size_t)dd * LQ;
        d0 = fmaf(qd, Krow[c0], d0);
        d1 = fmaf(qd, Krow[c1], d1);
    }
    float s0 = kv0 < 0 ? -1e30f : d0 * 0.125f;
    float s1 = kv1 < 0 ? -1e30f : d1 * 0.125f;

    // ---- softmax across the wave ----
    float mx = fmaxf(s0, s1);
    #pragma unroll
    for (int off = 32; off; off >>= 1) mx = fmaxf(mx, __shfl_xor(mx, off));
    float p0 = __expf(s0 - mx);
    float p1 = __expf(s1 - mx);
    float sum = p0 + p1;
    #pragma unroll
    for (int off = 32; off; off >>= 1) sum += __shfl_xor(sum, off);
    float inv = 1.0f / sum;
    sP[w][lane] = p0 * inv;
    sP[w][lane + 64] = p1 * inv;
    __syncthreads();

    // ---- PV: lane = d, loop kv slots (coalesced V reads) ----
    float acc = 0.f;
    const int sb = j >= (SPAN - 1) ? 0 : (SPAN - 1) - j;
    #pragma unroll 4
    for (int s = sb; s < SPAN; ++s) {
        int kv = j - (SPAN - 1) + s;
        acc = fmaf(sP[w][s], V[(size_t)kv * DHEAD + lane], acc);
    }

    int b = bh >> 3, h = bh & 7;
    O[((size_t)(b * LQ + j)) * DMODEL + h * DHEAD + lane] = f2bf(acc);
}

// ---------------------------------------------------------------------------
extern "C" void kernel_launch(void* const* d_in, const int* in_sizes, int n_in,
                              void* d_out, int out_size, void* d_ws, size_t ws_size,
                              hipStream_t stream) {
    const float* q  = (const float*)d_in[0];
    const float* k  = (const float*)d_in[1];
    const float* v  = (const float*)d_in[2];
    const float* Wq = (const float*)d_in[3];
    const float* Wk = (const float*)d_in[4];
    const float* Wv = (const float*)d_in[5];
    const float* Wo = (const float*)d_in[6];

    const size_t MK = (size_t)MROWS * DMODEL;   // 1M elems
    const size_t WK = (size_t)DMODEL * DMODEL;  // 256K elems

    unsigned short* Aq  = (unsigned short*)d_ws;
    unsigned short* Ak  = Aq + MK;
    unsigned short* Av  = Ak + MK;
    unsigned short* WtQ = Av + MK;
    unsigned short* WtK = WtQ + WK;
    unsigned short* WtV = WtK + WK;
    unsigned short* WtO = WtV + WK;
    float* Qp = (float*)(WtO + WK);
    float* Kt = Qp + MK;
    float* Vp = Kt + MK;
    unsigned short* Ah = Aq;   // alias: Aq dead after the Q projection

    cast_bf16_3<<<dim3(512, 3), 256, 0, stream>>>(q, k, v, Aq, Ak, Av);
    transposeW<<<dim3(8, 8, 4), 256, 0, stream>>>(Wq, Wk, Wv, Wo, WtQ, WtK, WtV, WtO);

    dim3 ggrid(DMODEL / 64, MROWS / 64);   // (8, 32) = 256 blocks
    gemm_bf16<1><<<ggrid, 256, 0, stream>>>(Aq, WtQ, Qp);
    gemm_bf16<2><<<ggrid, 256, 0, stream>>>(Ak, WtK, Kt);
    gemm_bf16<1><<<ggrid, 256, 0, stream>>>(Av, WtV, Vp);

    attn_win2<<<dim3(LQ / 4, 16), 256, 0, stream>>>(Qp, Kt, Vp, Ah);

    gemm_bf16<0><<<ggrid, 256, 0, stream>>>(Ah, WtO, (float*)d_out);
}

// Round 4
// 54.721 us; speedup vs baseline: 7.2655x; 2.5210x over previous
//
#include <hip/hip_runtime.h>
#include <hip/hip_bf16.h>

// B=2, LQ=LKV=1024, H=8, DQK=DV=64, DQ=DK=DVIN=DOUT=512, SPAN=128, STRIDE=1
#define LQ 1024
#define NH 8
#define DHEAD 64
#define DMODEL 512
#define SPAN 128
#define MROWS 2048   // B*LQ

typedef __attribute__((ext_vector_type(8))) short   bf16x8;
typedef __attribute__((ext_vector_type(4))) float   f32x4;
typedef __attribute__((ext_vector_type(8))) unsigned short us8;

static __device__ __forceinline__ unsigned short f2bf(float f) {
    union { __hip_bfloat16 h; unsigned short u; } cv;
    cv.h = __float2bfloat16(f);
    return cv.u;
}

static __device__ __forceinline__ void gload_lds16(const void* g, void* l) {
    __builtin_amdgcn_global_load_lds((const __attribute__((address_space(1))) void*)g,
                                     (__attribute__((address_space(3))) void*)l, 16, 0, 0);
}

// ---------------------------------------------------------------------------
// Prep 1: cast q,k,v (f32 [2048][512]) -> bf16
// ---------------------------------------------------------------------------
__global__ __launch_bounds__(256) void cast_bf16_3(
    const float* __restrict__ q, const float* __restrict__ k, const float* __restrict__ v,
    unsigned short* __restrict__ Aq, unsigned short* __restrict__ Ak, unsigned short* __restrict__ Av)
{
    const float* src = blockIdx.y == 0 ? q : (blockIdx.y == 1 ? k : v);
    unsigned short* dst = blockIdx.y == 0 ? Aq : (blockIdx.y == 1 ? Ak : Av);
    int i = (blockIdx.x * 256 + threadIdx.x) * 8;
    float4 f0 = *(const float4*)&src[i];
    float4 f1 = *(const float4*)&src[i + 4];
    us8 o;
    o[0] = f2bf(f0.x); o[1] = f2bf(f0.y); o[2] = f2bf(f0.z); o[3] = f2bf(f0.w);
    o[4] = f2bf(f1.x); o[5] = f2bf(f1.y); o[6] = f2bf(f1.z); o[7] = f2bf(f1.w);
    *(us8*)&dst[i] = o;
}

// ---------------------------------------------------------------------------
// Prep 2: transpose+cast weights: Wt[n][k] = bf16(W[k][n]), 512x512 each
// ---------------------------------------------------------------------------
__global__ __launch_bounds__(256) void transposeW(
    const float* __restrict__ W0, const float* __restrict__ W1,
    const float* __restrict__ W2, const float* __restrict__ W3,
    unsigned short* __restrict__ T0, unsigned short* __restrict__ T1,
    unsigned short* __restrict__ T2, unsigned short* __restrict__ T3)
{
    const float* W = blockIdx.z == 0 ? W0 : blockIdx.z == 1 ? W1 : blockIdx.z == 2 ? W2 : W3;
    unsigned short* T = blockIdx.z == 0 ? T0 : blockIdx.z == 1 ? T1 : blockIdx.z == 2 ? T2 : T3;
    __shared__ unsigned short sT[64][72];
    int c = threadIdx.x & 63;
    int r0 = (threadIdx.x >> 6) * 16;
    int n0 = blockIdx.x * 64, k0 = blockIdx.y * 64;
    #pragma unroll
    for (int i = 0; i < 16; ++i) {
        int r = r0 + i;
        sT[c][r] = f2bf(W[(size_t)(k0 + r) * DMODEL + n0 + c]);
    }
    __syncthreads();
    #pragma unroll
    for (int i = 0; i < 16; ++i) {
        int r = r0 + i;
        T[(size_t)(n0 + r) * DMODEL + k0 + c] = sT[r][c];
    }
}

// ---------------------------------------------------------------------------
// bf16 MFMA GEMM: C[M=2048][N=512] = A[M][K=512] @ W[K][N], A bf16 row-major,
// Bt = W^T bf16 [N][K] row-major. Tile 64x64, BK=64, 4 waves (2x2), dbuf LDS.
// MODE 0: C f32 row-major.
// MODE 1: scatter bf16 to (B,H,LQ,64).
// MODE 2: write C^T (swapped operands) bf16 to (B,H,64,LQ).
// (unchanged from round 2/3 — validated incl. post-timing in round 2)
// ---------------------------------------------------------------------------
template<int MODE>
__global__ __launch_bounds__(256) void gemm_bf16(
    const unsigned short* __restrict__ A, const unsigned short* __restrict__ Bt,
    void* __restrict__ Cv)
{
    __shared__ unsigned short As[2][4096];   // 64 rows x 64 k, swizzled, 8 KB each
    __shared__ unsigned short Bs[2][4096];

    const int tid = threadIdx.x;
    const int lane = tid & 63;
    const int w = tid >> 6;           // 4 waves
    const int wm = w >> 1, wn = w & 1;
    const int m0 = blockIdx.y * 64;
    const int n0 = blockIdx.x * 64;

    const int srow = lane >> 3;          // 0..7
    const int sgrp = (lane & 7) ^ srow;  // pre-swizzled global k-group

    f32x4 acc[2][2];
    #pragma unroll
    for (int i = 0; i < 2; ++i)
        #pragma unroll
        for (int j = 0; j < 2; ++j)
            acc[i][j] = f32x4{0.f, 0.f, 0.f, 0.f};

    auto stage = [&](int buf, int kt) {
        const int k0 = kt * 64;
        #pragma unroll
        for (int cc = 0; cc < 2; ++cc) {
            int call = w * 2 + cc;
            int row = call * 8 + srow;
            const unsigned short* gA = A + (size_t)(m0 + row) * DMODEL + k0 + (sgrp << 3);
            gload_lds16(gA, &As[buf][call * 512]);
            const unsigned short* gB = Bt + (size_t)(n0 + row) * DMODEL + k0 + (sgrp << 3);
            gload_lds16(gB, &Bs[buf][call * 512]);
        }
    };

    const int frow = lane & 15;
    const int fkg  = lane >> 4;

    auto ldfrag = [&](const unsigned short* base, int rb, int ks) -> bf16x8 {
        int row = rb * 16 + frow;
        int kg = ks * 4 + fkg;
        int off = row * 64 + ((kg ^ (row & 7)) << 3);
        return *(const bf16x8*)&base[off];
    };

    stage(0, 0);
    __syncthreads();

    for (int kt = 0; kt < 8; ++kt) {
        int buf = kt & 1;
        if (kt < 7) stage(buf ^ 1, kt + 1);
        #pragma unroll
        for (int ks = 0; ks < 2; ++ks) {
            bf16x8 a0, a1, b0, b1;
            if constexpr (MODE == 2) {
                a0 = ldfrag(Bs[buf], wn * 2 + 0, ks);
                a1 = ldfrag(Bs[buf], wn * 2 + 1, ks);
                b0 = ldfrag(As[buf], wm * 2 + 0, ks);
                b1 = ldfrag(As[buf], wm * 2 + 1, ks);
            } else {
                a0 = ldfrag(As[buf], wm * 2 + 0, ks);
                a1 = ldfrag(As[buf], wm * 2 + 1, ks);
                b0 = ldfrag(Bs[buf], wn * 2 + 0, ks);
                b1 = ldfrag(Bs[buf], wn * 2 + 1, ks);
            }
            acc[0][0] = __builtin_amdgcn_mfma_f32_16x16x32_bf16(a0, b0, acc[0][0], 0, 0, 0);
            acc[0][1] = __builtin_amdgcn_mfma_f32_16x16x32_bf16(a0, b1, acc[0][1], 0, 0, 0);
            acc[1][0] = __builtin_amdgcn_mfma_f32_16x16x32_bf16(a1, b0, acc[1][0], 0, 0, 0);
            acc[1][1] = __builtin_amdgcn_mfma_f32_16x16x32_bf16(a1, b1, acc[1][1], 0, 0, 0);
        }
        __syncthreads();
    }

    // C/D layout: col = lane&15, row = (lane>>4)*4 + r
    #pragma unroll
    for (int i = 0; i < 2; ++i) {
        #pragma unroll
        for (int j = 0; j < 2; ++j) {
            #pragma unroll
            for (int r = 0; r < 4; ++r) {
                if constexpr (MODE == 2) {
                    int n = n0 + wn * 32 + i * 16 + (lane >> 4) * 4 + r;
                    int m = m0 + wm * 32 + j * 16 + (lane & 15);
                    int b = m >> 10, jq = m & 1023, h = n >> 6, d = n & 63;
                    ((unsigned short*)Cv)[(((size_t)(b * NH + h) * DHEAD) + d) * LQ + jq] = f2bf(acc[i][j][r]);
                } else {
                    int m = m0 + wm * 32 + i * 16 + (lane >> 4) * 4 + r;
                    int n = n0 + wn * 32 + j * 16 + (lane & 15);
                    if constexpr (MODE == 1) {
                        int b = m >> 10, jq = m & 1023, h = n >> 6, d = n & 63;
                        ((unsigned short*)Cv)[(((size_t)(b * NH + h) * LQ) + jq) * DHEAD + d] = f2bf(acc[i][j][r]);
                    } else {
                        ((float*)Cv)[(size_t)m * DMODEL + n] = acc[i][j][r];
                    }
                }
            }
        }
    }
}

// ---------------------------------------------------------------------------
// MFMA sliding-window attention, v2 (race-hardened).
// Block: 4 waves, 64 queries (wave w owns 16). Key tile: 192 kv.
// Qp, Kp: bf16 (BH, LQ, 64); Vt: bf16 (BH, 64, LQ); O: bf16 (B, LQ, 512).
// Changes vs v1: NO LDS aliasing (Ps separate), NO global_load_lds —
// register staging with swizzled ds_write; zero-fill out-of-window tiles.
// Single barrier after staging; Ps is wave-private.
// ---------------------------------------------------------------------------
__global__ __launch_bounds__(256) void attn_mfma(
    const unsigned short* __restrict__ Qp, const unsigned short* __restrict__ Kp,
    const unsigned short* __restrict__ Vt, unsigned short* __restrict__ O)
{
    __shared__ __align__(16) unsigned short Ks[192 * 64];   // 24576 B, XOR-swizzled
    __shared__ __align__(16) unsigned short Vs[64 * 192];   // 24576 B, XOR-swizzled
    __shared__ __align__(16) unsigned short Ps[64 * 200];   // 25600 B, padded rows

    const int tid = threadIdx.x;
    const int lane = tid & 63;
    const int w = tid >> 6;
    const int bh = blockIdx.y;
    const int j0 = blockIdx.x * 64;
    const int kv0 = j0 - 128;

    const unsigned short* Kg = Kp + (size_t)bh * LQ * DHEAD;
    const unsigned short* Vg = Vt + (size_t)bh * DHEAD * LQ;

    const us8 zz = {0, 0, 0, 0, 0, 0, 0, 0};

    // ---- load K tile [192 rows][64] to registers (6 x 16B chunks/thread) ----
    us8 kreg[6];
    #pragma unroll
    for (int i = 0; i < 6; ++i) {
        int c = i * 256 + tid;              // chunk 0..1535
        int row = c >> 3, g = c & 7;
        int grow = kv0 + row;
        us8 t = zz;
        if (grow >= 0) t = *(const us8*)&Kg[(size_t)grow * DHEAD + g * 8];
        kreg[i] = t;
    }
    // ---- load V^T tile [64 d][192 kv] to registers ----
    us8 vreg[6];
    #pragma unroll
    for (int i = 0; i < 6; ++i) {
        int c = i * 256 + tid;
        int d = c / 24, g = c - d * 24;     // g: kv-chunk 0..23
        int col = kv0 + g * 8;              // kv0 is 8-aligned -> chunk fully in/out
        us8 t = zz;
        if (col >= 0) t = *(const us8*)&Vg[(size_t)d * LQ + col];
        vreg[i] = t;
    }
    // ---- ds_write with XOR swizzle ----
    #pragma unroll
    for (int i = 0; i < 6; ++i) {
        int c = i * 256 + tid;
        int row = c >> 3, g = c & 7;
        *(us8*)&Ks[row * 64 + ((g ^ (row & 7)) << 3)] = kreg[i];
    }
    #pragma unroll
    for (int i = 0; i < 6; ++i) {
        int c = i * 256 + tid;
        int d = c / 24, g = c - d * 24;
        int sg = (g & ~7) | ((g & 7) ^ (d & 7));
        *(us8*)&Vs[d * 192 + sg * 8] = vreg[i];
    }

    const int frow = lane & 15, fkg = lane >> 4;

    // ---- Q fragments straight from global ----
    bf16x8 qa[2];
    {
        const unsigned short* Qrow = Qp + ((size_t)bh * LQ + j0 + w * 16 + frow) * DHEAD;
        qa[0] = *(const bf16x8*)&Qrow[fkg * 8];
        qa[1] = *(const bf16x8*)&Qrow[32 + fkg * 8];
    }

    __syncthreads();   // staging complete

    // ---- S = Q K^T over 12 kv blocks ----
    f32x4 sacc[12];
    #pragma unroll
    for (int b = 0; b < 12; ++b) sacc[b] = f32x4{0.f, 0.f, 0.f, 0.f};
    #pragma unroll
    for (int b = 0; b < 12; ++b) {
        #pragma unroll
        for (int ks = 0; ks < 2; ++ks) {
            int row = b * 16 + frow;
            int kg = ks * 4 + fkg;
            bf16x8 kb = *(const bf16x8*)&Ks[row * 64 + ((kg ^ (row & 7)) << 3)];
            sacc[b] = __builtin_amdgcn_mfma_f32_16x16x32_bf16(qa[ks], kb, sacc[b], 0, 0, 0);
        }
    }

    // ---- mask + softmax (row = query, spread over 16 lanes x 12 regs) ----
    #pragma unroll
    for (int r = 0; r < 4; ++r) {
        int q = w * 16 + fkg * 4 + r;          // query within 64-tile
        float sv[12];
        float mx = -1e30f;
        #pragma unroll
        for (int b = 0; b < 12; ++b) {
            int rel = b * 16 + frow - 128 - q;          // kv - j
            int kvabs = kv0 + b * 16 + frow;
            bool valid = (rel <= 0) & (rel >= -(SPAN - 1)) & (kvabs >= 0);
            float s = valid ? sacc[b][r] * 0.125f : -1e30f;
            sv[b] = s;
            mx = fmaxf(mx, s);
        }
        #pragma unroll
        for (int off = 1; off < 16; off <<= 1) mx = fmaxf(mx, __shfl_xor(mx, off));
        float sum = 0.f;
        #pragma unroll
        for (int b = 0; b < 12; ++b) { float p = __expf(sv[b] - mx); sv[b] = p; sum += p; }
        #pragma unroll
        for (int off = 1; off < 16; off <<= 1) sum += __shfl_xor(sum, off);
        float inv = 1.0f / sum;
        #pragma unroll
        for (int b = 0; b < 12; ++b) sacc[b][r] = sv[b] * inv;
    }

    // ---- P -> bf16 into its own LDS buffer (wave-private rows) ----
    #pragma unroll
    for (int b = 0; b < 12; ++b) {
        #pragma unroll
        for (int r = 0; r < 4; ++r) {
            int q = w * 16 + fkg * 4 + r;
            Ps[q * 200 + b * 16 + frow] = f2bf(sacc[b][r]);
        }
    }
    // no barrier needed: each wave reads only its own 16 Ps rows (lgkm-ordered)

    // ---- O = P V ----
    f32x4 oacc[4];
    #pragma unroll
    for (int nb = 0; nb < 4; ++nb) oacc[nb] = f32x4{0.f, 0.f, 0.f, 0.f};
    #pragma unroll
    for (int kb = 0; kb < 6; ++kb) {
        int q = w * 16 + frow;
        bf16x8 pa = *(const bf16x8*)&Ps[q * 200 + (kb * 4 + fkg) * 8];
        #pragma unroll
        for (int nb = 0; nb < 4; ++nb) {
            int d = nb * 16 + frow;
            int g = kb * 4 + fkg;
            int sg = (g & ~7) | ((g & 7) ^ (d & 7));
            bf16x8 vb = *(const bf16x8*)&Vs[d * 192 + sg * 8];
            oacc[nb] = __builtin_amdgcn_mfma_f32_16x16x32_bf16(pa, vb, oacc[nb], 0, 0, 0);
        }
    }

    // ---- write O (B, LQ, 512) bf16 ----
    int b = bh >> 3, h = bh & 7;
    #pragma unroll
    for (int nb = 0; nb < 4; ++nb) {
        #pragma unroll
        for (int r = 0; r < 4; ++r) {
            int jq = j0 + w * 16 + fkg * 4 + r;
            int col = h * 64 + nb * 16 + frow;
            O[(size_t)(b * LQ + jq) * DMODEL + col] = f2bf(oacc[nb][r]);
        }
    }
}

// ---------------------------------------------------------------------------
extern "C" void kernel_launch(void* const* d_in, const int* in_sizes, int n_in,
                              void* d_out, int out_size, void* d_ws, size_t ws_size,
                              hipStream_t stream) {
    const float* q  = (const float*)d_in[0];
    const float* k  = (const float*)d_in[1];
    const float* v  = (const float*)d_in[2];
    const float* Wq = (const float*)d_in[3];
    const float* Wk = (const float*)d_in[4];
    const float* Wv = (const float*)d_in[5];
    const float* Wo = (const float*)d_in[6];

    const size_t MK = (size_t)MROWS * DMODEL;   // 1M elems
    const size_t WK = (size_t)DMODEL * DMODEL;  // 256K elems

    unsigned short* Aq  = (unsigned short*)d_ws;
    unsigned short* Ak  = Aq + MK;
    unsigned short* Av  = Ak + MK;
    unsigned short* WtQ = Av + MK;
    unsigned short* WtK = WtQ + WK;
    unsigned short* WtV = WtK + WK;
    unsigned short* WtO = WtV + WK;
    unsigned short* Qp  = WtO + WK;
    unsigned short* Kp  = Qp + MK;
    unsigned short* Vt  = Kp + MK;
    unsigned short* Ah  = Aq;   // alias: Aq dead after the Q projection

    cast_bf16_3<<<dim3(512, 3), 256, 0, stream>>>(q, k, v, Aq, Ak, Av);
    transposeW<<<dim3(8, 8, 4), 256, 0, stream>>>(Wq, Wk, Wv, Wo, WtQ, WtK, WtV, WtO);

    dim3 ggrid(DMODEL / 64, MROWS / 64);   // (8, 32) = 256 blocks
    gemm_bf16<1><<<ggrid, 256, 0, stream>>>(Aq, WtQ, Qp);
    gemm_bf16<1><<<ggrid, 256, 0, stream>>>(Ak, WtK, Kp);
    gemm_bf16<2><<<ggrid, 256, 0, stream>>>(Av, WtV, Vt);

    attn_mfma<<<dim3(LQ / 64, 16), 256, 0, stream>>>(Qp, Kp, Vt, Ah);

    gemm_bf16<0><<<ggrid, 256, 0, stream>>>(Ah, WtO, (float*)d_out);
}